// Round 6
// baseline (141.525 us; speedup 1.0000x reference)
//
#include <hip/hip_runtime.h>
#include <hip/hip_bf16.h>
#include <stdint.h>

#define NTOK 4096
#define DIM  1024

typedef unsigned short u16;
typedef __bf16 bf16x8 __attribute__((ext_vector_type(8)));
typedef float f32x4 __attribute__((ext_vector_type(4)));
typedef u16 u16x8 __attribute__((ext_vector_type(8)));

// ---------- helpers ----------
__device__ __forceinline__ u16 f2bf(float f) {
  union { float f; uint32_t u; } c; c.f = f;
  return (u16)((c.u + 0x7fffu + ((c.u >> 16) & 1u)) >> 16);  // RNE
}
__device__ __forceinline__ float bf2f(u16 b) {
  union { uint32_t u; float f; } c; c.u = (uint32_t)b << 16;
  return c.f;
}

__device__ __forceinline__ float wave_max(float v) {
#pragma unroll
  for (int o = 32; o; o >>= 1) v = fmaxf(v, __shfl_xor(v, o, 64));
  return v;
}
__device__ __forceinline__ float wave_sum(float v) {
#pragma unroll
  for (int o = 32; o; o >>= 1) v += __shfl_xor(v, o, 64);
  return v;
}

// bijective XCD swizzle (m204)
__device__ __forceinline__ int xcd_swz(int orig, int nwg) {
  const int q = nwg >> 3, r = nwg & 7;
  const int x = orig & 7, i = orig >> 3;
  return (x < r ? x * (q + 1) : r * (q + 1) + (x - r) * q) + i;
}

// async global->LDS, 16B/lane; LDS dest wave-uniform base (HW adds lane*16).
__device__ __forceinline__ void gld16(const u16* g, u16* l) {
  __builtin_amdgcn_global_load_lds((const __attribute__((address_space(1))) void*)g,
                                   (__attribute__((address_space(3))) void*)l, 16, 0, 0);
}

template<int N> __device__ __forceinline__ void wait_vmcnt() {
  if constexpr (N == 0) asm volatile("s_waitcnt vmcnt(0)" ::: "memory");
  else if constexpr (N == 3) asm volatile("s_waitcnt vmcnt(3)" ::: "memory");
  else if constexpr (N == 4) asm volatile("s_waitcnt vmcnt(4)" ::: "memory");
  else if constexpr (N == 6) asm volatile("s_waitcnt vmcnt(6)" ::: "memory");
  else if constexpr (N == 8) asm volatile("s_waitcnt vmcnt(8)" ::: "memory");
}

// ============================================================================
// fp32 -> bf16 conversion, 8 elems/thread. z selects tensor.
// ============================================================================
__global__ __launch_bounds__(256) void cvt6(
    const float* __restrict__ qx, const float* __restrict__ kx, const float* __restrict__ vx,
    const float* __restrict__ Wq, const float* __restrict__ Wk, const float* __restrict__ Wv,
    u16* __restrict__ qxb, u16* __restrict__ kxb, u16* __restrict__ vxb,
    u16* __restrict__ Wqb, u16* __restrict__ Wkb, u16* __restrict__ Wvb)
{
  const int z = blockIdx.z;
  const int nelem = (z < 3) ? NTOK * DIM : DIM * DIM;
  const int i = (blockIdx.x * 256 + threadIdx.x) * 8;
  if (i >= nelem) return;
  const float* in = (z == 0) ? qx : (z == 1) ? kx : (z == 2) ? vx
                  : (z == 3) ? Wq : (z == 4) ? Wk : Wv;
  u16* out = (z == 0) ? qxb : (z == 1) ? kxb : (z == 2) ? vxb
           : (z == 3) ? Wqb : (z == 4) ? Wkb : Wvb;
  float4 a = *reinterpret_cast<const float4*>(in + i);
  float4 b = *reinterpret_cast<const float4*>(in + i + 4);
  u16x8 o;
  o[0] = f2bf(a.x); o[1] = f2bf(a.y); o[2] = f2bf(a.z); o[3] = f2bf(a.w);
  o[4] = f2bf(b.x); o[5] = f2bf(b.y); o[6] = f2bf(b.z); o[7] = f2bf(b.w);
  *reinterpret_cast<u16x8*>(out + i) = o;
}

// ============================================================================
// BMx128xK core, 3-DEEP COUNTED-VMCNT PIPELINE (T4): tiles t+1, t+2 stay in
// flight across barriers; vmcnt never drains to 0 in steady state.
// BK=32. 3 LDS buffers, each [A: BM*32 | B: 128*32] bf16.
// Staging: global_load_lds(16B), linear LDS dest (lane l -> row l>>2, chunk
// l&3 of a 16-row stripe), pre-swizzled GLOBAL source chunk (l&3)^((l>>3)&3).
// Read swizzle: physical chunk = c ^ ((r>>1)&3) -> 2-way bank alias (free).
// Per K-step per wave: LPS gload_lds, {BM/32 + 4} ds_read_b128, BM/8 MFMA.
// Loop: [waitcnt vmcnt(ahead>=2 ? 2*LPS : ahead*LPS)] barrier; sched_barrier;
//       ds_read+MFMA(buf t%3); barrier; stage(t+3 -> buf t%3).
// ============================================================================
template<int BM>
__device__ __forceinline__ void mm_core(
    const u16* __restrict__ A, const u16* __restrict__ B,
    int lda, int ldb, int klo, int khi, int row0, int col0,
    u16* lds, f32x4 (&acc)[BM / 32][4])
{
  constexpr int ABUF = BM * 32;          // elems per A region
  constexpr int BUFSZ = ABUF + 128 * 32; // one stage buffer
  constexpr int RPW_A = BM / 4;          // A rows per wave stripe
  constexpr int LPS = BM / 64 + 2;       // loads per stage per wave (A + 2 B)
  const int tid = threadIdx.x;
  const int wave = tid >> 6, lane = tid & 63;
  const int wr = wave >> 1, wc = wave & 1;
  const int l15 = lane & 15, l4 = lane >> 4;

  // staging: lane -> row lane>>2 (of a 16-row group), global chunk pre-swizzled
  const int srow = lane >> 2;
  const int gchunk = ((lane & 3) ^ ((lane >> 3) & 3)) << 3;  // elem offset
  const u16* gA = A + (size_t)(row0 + wave * RPW_A + srow) * lda + gchunk;
  const u16* gB = B + (size_t)(col0 + wave * 32 + srow) * ldb + gchunk;
  const int lbA = wave * RPW_A * 32;
  const int lbB = ABUF + wave * 32 * 32;

  const int nsteps = (khi - klo) >> 5;

  auto stage = [&](int s, u16* buf) {
    const int k = klo + (s << 5);
#pragma unroll
    for (int i = 0; i < RPW_A / 16; ++i)
      gld16(gA + (size_t)(i * 16) * lda + k, buf + lbA + i * 16 * 32);
#pragma unroll
    for (int i = 0; i < 2; ++i)
      gld16(gB + (size_t)(i * 16) * ldb + k, buf + lbB + i * 16 * 32);
  };

  // prologue: stage up to 3 tiles
  if (0 < nsteps) stage(0, lds);
  if (1 < nsteps) stage(1, lds + BUFSZ);
  if (2 < nsteps) stage(2, lds + 2 * BUFSZ);

  int cur = 0;  // t % 3
  for (int t = 0; t < nsteps; ++t) {
    const int ahead = nsteps - 1 - t;
    if (ahead >= 2)      wait_vmcnt<2 * LPS>();
    else if (ahead == 1) wait_vmcnt<LPS>();
    else                 wait_vmcnt<0>();
    __builtin_amdgcn_s_barrier();         // all waves' tile-t loads complete
    __builtin_amdgcn_sched_barrier(0);    // pin ds_reads below the barrier
    const char* buf = (const char*)(lds + cur * BUFSZ);

    bf16x8 af[BM / 32], bfv[4];
#pragma unroll
    for (int mf = 0; mf < BM / 32; ++mf) {
      const int r = wr * (BM / 2) + mf * 16 + l15;
      af[mf] = *reinterpret_cast<const bf16x8*>(
          buf + (r << 6) + (((l4 ^ (r >> 1)) & 3) << 4));
    }
#pragma unroll
    for (int nf = 0; nf < 4; ++nf) {
      const int r = wc * 64 + nf * 16 + l15;
      bfv[nf] = *reinterpret_cast<const bf16x8*>(
          buf + 2 * ABUF + (r << 6) + (((l4 ^ (r >> 1)) & 3) << 4));
    }
#pragma unroll
    for (int mf = 0; mf < BM / 32; ++mf)
#pragma unroll
      for (int nf = 0; nf < 4; ++nf)
        acc[mf][nf] = __builtin_amdgcn_mfma_f32_16x16x32_bf16(af[mf], bfv[nf], acc[mf][nf], 0, 0, 0);

    __builtin_amdgcn_s_barrier();         // all waves done reading buf[cur]
    if (t + 3 < nsteps) stage(t + 3, lds + cur * BUFSZ);
    cur = (cur == 2) ? 0 : cur + 1;
  }
}

// ============================================================================
// Projections: y = x @ W^T, bf16 in/out. 1-D grid 768, XCD-swizzled.
// z=2 stores v transposed [DIM,NTOK] for the PV B-operand.
// ============================================================================
__global__ __launch_bounds__(256) void proj_sw(
    const u16* __restrict__ qxb, const u16* __restrict__ kxb, const u16* __restrict__ vxb,
    const u16* __restrict__ Wqb, const u16* __restrict__ Wkb, const u16* __restrict__ Wvb,
    u16* __restrict__ qb, u16* __restrict__ kb, u16* __restrict__ vT)
{
  __shared__ alignas(16) u16 lds[3 * 256 * 32];
  const int w = xcd_swz(blockIdx.x, 768);
  const int z = w >> 8, rem = w & 255;
  const int by = rem >> 3, bx = rem & 7;
  const u16* A = (z == 0) ? qxb : (z == 1) ? kxb : vxb;
  const u16* B = (z == 0) ? Wqb : (z == 1) ? Wkb : Wvb;
  const int row0 = by * 128, col0 = bx * 128;

  f32x4 acc[4][4] = {};
  mm_core<128>(A, B, DIM, DIM, 0, DIM, row0, col0, lds, acc);

  const int lane = threadIdx.x & 63;
  const int wave = threadIdx.x >> 6;
  const int l15 = lane & 15, l4 = lane >> 4;
  const int om = row0 + (wave >> 1) * 64;
  const int on = col0 + (wave & 1) * 64;
  if (z < 2) {
    u16* C = (z == 0) ? qb : kb;
#pragma unroll
    for (int mf = 0; mf < 4; ++mf)
#pragma unroll
      for (int nf = 0; nf < 4; ++nf)
#pragma unroll
        for (int r = 0; r < 4; ++r)
          C[(size_t)(om + mf * 16 + l4 * 4 + r) * DIM + (on + nf * 16 + l15)] = f2bf(acc[mf][nf][r]);
  } else {  // v transposed: 4 consecutive rows -> contiguous 8B store
#pragma unroll
    for (int mf = 0; mf < 4; ++mf)
#pragma unroll
      for (int nf = 0; nf < 4; ++nf) {
        ushort4 o;
        o.x = f2bf(acc[mf][nf][0]);
        o.y = f2bf(acc[mf][nf][1]);
        o.z = f2bf(acc[mf][nf][2]);
        o.w = f2bf(acc[mf][nf][3]);
        *reinterpret_cast<ushort4*>(&vT[(size_t)(on + nf * 16 + l15) * NTOK + (om + mf * 16 + l4 * 4)]) = o;
      }
  }
}

// ============================================================================
// Scores: S = (q @ k^T) * scale, bf16 out. 528 lower-triangle tiles.
// ============================================================================
__global__ __launch_bounds__(256) void gemm_scores(
    const u16* __restrict__ A, const u16* __restrict__ B, u16* __restrict__ C, float scale)
{
  __shared__ alignas(16) u16 lds[3 * 256 * 32];
  const int t = xcd_swz(blockIdx.x, 528);
  int by = (int)((sqrtf(8.0f * t + 1.0f) - 1.0f) * 0.5f);
  while ((by + 1) * (by + 2) / 2 <= t) ++by;
  while (by * (by + 1) / 2 > t) --by;
  const int bx = t - by * (by + 1) / 2;
  const int row0 = by * 128, col0 = bx * 128;

  f32x4 acc[4][4] = {};
  mm_core<128>(A, B, DIM, DIM, 0, DIM, row0, col0, lds, acc);

  const int lane = threadIdx.x & 63;
  const int wave = threadIdx.x >> 6;
  const int l15 = lane & 15, l4 = lane >> 4;
  const int om = row0 + (wave >> 1) * 64;
  const int on = col0 + (wave & 1) * 64;
#pragma unroll
  for (int mf = 0; mf < 4; ++mf)
#pragma unroll
    for (int nf = 0; nf < 4; ++nf)
#pragma unroll
      for (int r = 0; r < 4; ++r)
        C[(size_t)(om + mf * 16 + l4 * 4 + r) * NTOK + (on + nf * 16 + l15)] = f2bf(acc[mf][nf][r] * scale);
}

// ============================================================================
// PV: out = P @ vT^T. 64x128 tiles, 1-D grid 768 = 96 chunks x 8 bx.
// by<32: single chunk. by>=32: 2-way split-K, both halves atomicAdd into
// pre-zeroed out (2 addends -> commutative -> deterministic).
// ============================================================================
__global__ __launch_bounds__(256) void gemm_pv(
    const u16* __restrict__ P, const u16* __restrict__ vT, float* __restrict__ C)
{
  __shared__ alignas(16) u16 lds[3 * 192 * 32];
  const int w = xcd_swz(blockIdx.x, 768);
  const int bx = w & 7;
  const int cid = w >> 3;  // 0..95
  int by, half;
  if (cid < 32) { by = cid; half = -1; }
  else { const int j = cid - 32; by = 32 + (j >> 1); half = j & 1; }
  const int row0 = by * 64, col0 = bx * 128;
  const int Klim = row0 + 64;
  int klo = 0, khi = Klim;
  if (half >= 0) {
    const int h1 = (((Klim >> 6) + 1) >> 1) << 6;  // ceil(ntiles64/2)*64
    if (half == 0) khi = h1; else klo = h1;
  }

  f32x4 acc[2][4] = {};
  mm_core<64>(P, vT, NTOK, NTOK, klo, khi, row0, col0, lds, acc);

  const int lane = threadIdx.x & 63;
  const int wave = threadIdx.x >> 6;
  const int l15 = lane & 15, l4 = lane >> 4;
  const int om = row0 + (wave >> 1) * 32;
  const int on = col0 + (wave & 1) * 64;
#pragma unroll
  for (int mf = 0; mf < 2; ++mf)
#pragma unroll
    for (int nf = 0; nf < 4; ++nf)
#pragma unroll
      for (int r = 0; r < 4; ++r) {
        const size_t idx = (size_t)(om + mf * 16 + l4 * 4 + r) * DIM + (on + nf * 16 + l15);
        if (half >= 0) atomicAdd(&C[idx], acc[mf][nf][r]);
        else C[idx] = acc[mf][nf][r];
      }
}

// ---------- causal row softmax: S bf16 -> P bf16, cols < (row&~127)+128 ----------
__global__ __launch_bounds__(256) void softmax_causal(const u16* __restrict__ S,
                                                      u16* __restrict__ P) {
  __shared__ float buf[NTOK];
  __shared__ float red[8];
  const int row = blockIdx.x;
  const int tid = threadIdx.x;
  const int limit = row + 1;
  const int limit128 = (row & ~127) + 128;
  const u16* srow = S + (size_t)row * NTOK;

  float lmax = -1e30f;
  for (int j = tid * 8; j < limit128; j += 2048) {
    float v[8];
    if (j + 8 <= limit) {
      u16x8 sv = *reinterpret_cast<const u16x8*>(srow + j);
#pragma unroll
      for (int e = 0; e < 8; ++e) v[e] = bf2f(sv[e]);
    } else {
#pragma unroll
      for (int e = 0; e < 8; ++e) v[e] = (j + e < limit) ? bf2f(srow[j + e]) : -1e30f;
    }
    float4 lo = {v[0], v[1], v[2], v[3]}, hi = {v[4], v[5], v[6], v[7]};
    *reinterpret_cast<float4*>(buf + j) = lo;
    *reinterpret_cast<float4*>(buf + j + 4) = hi;
#pragma unroll
    for (int e = 0; e < 8; ++e) lmax = fmaxf(lmax, v[e]);
  }
  lmax = wave_max(lmax);
  if ((tid & 63) == 0) red[tid >> 6] = lmax;
  __syncthreads();
  const float m = fmaxf(fmaxf(red[0], red[1]), fmaxf(red[2], red[3]));

  float lsum = 0.f;
  for (int j = tid * 8; j < limit128; j += 2048) {
    float4 lo = *reinterpret_cast<float4*>(buf + j);
    float4 hi = *reinterpret_cast<float4*>(buf + j + 4);
    float e0 = __expf(lo.x - m), e1 = __expf(lo.y - m), e2 = __expf(lo.z - m), e3 = __expf(lo.w - m);
    float e4 = __expf(hi.x - m), e5 = __expf(hi.y - m), e6 = __expf(hi.z - m), e7 = __expf(hi.w - m);
    float4 eo = {e0, e1, e2, e3}, eh = {e4, e5, e6, e7};
    *reinterpret_cast<float4*>(buf + j) = eo;
    *reinterpret_cast<float4*>(buf + j + 4) = eh;
    lsum += ((e0 + e1) + (e2 + e3)) + ((e4 + e5) + (e6 + e7));
  }
  lsum = wave_sum(lsum);
  if ((tid & 63) == 0) red[4 + (tid >> 6)] = lsum;
  __syncthreads();
  const float inv = 1.0f / (red[4] + red[5] + red[6] + red[7]);

  u16* prow = P + (size_t)row * NTOK;
  for (int j = tid * 8; j < limit128; j += 2048) {
    float4 lo = *reinterpret_cast<float4*>(buf + j);
    float4 hi = *reinterpret_cast<float4*>(buf + j + 4);
    u16x8 o;
    o[0] = f2bf(lo.x * inv); o[1] = f2bf(lo.y * inv);
    o[2] = f2bf(lo.z * inv); o[3] = f2bf(lo.w * inv);
    o[4] = f2bf(hi.x * inv); o[5] = f2bf(hi.y * inv);
    o[6] = f2bf(hi.z * inv); o[7] = f2bf(hi.w * inv);
    *reinterpret_cast<u16x8*>(prow + j) = o;
  }
}

// ---------- launcher ----------
extern "C" void kernel_launch(void* const* d_in, const int* in_sizes, int n_in,
                              void* d_out, int out_size, void* d_ws, size_t ws_size,
                              hipStream_t stream) {
  const float* qx = (const float*)d_in[0];
  const float* kx = (const float*)d_in[1];
  const float* vx = (const float*)d_in[2];
  const float* Wq = (const float*)d_in[3];
  const float* Wk = (const float*)d_in[4];
  const float* Wv = (const float*)d_in[5];
  float* out = (float*)d_out;
  char* ws = (char*)d_ws;
  const size_t MB = 1024ull * 1024ull;

  if (ws_size < 120 * MB) {
    hipMemsetAsync(d_out, 0xFF, (size_t)out_size * sizeof(float), stream);
    return;
  }

  // ws layout: [0,30) cvt bf16 (dead after proj) | [0,32) S bf16 (after proj)
  //            [64,72) qb | [72,80) kb | [80,88) vT | [88,120) P
  u16* qxb = (u16*)(ws);
  u16* kxb = (u16*)(ws + 8 * MB);
  u16* vxb = (u16*)(ws + 16 * MB);
  u16* Wqb = (u16*)(ws + 24 * MB);
  u16* Wkb = (u16*)(ws + 26 * MB);
  u16* Wvb = (u16*)(ws + 28 * MB);
  u16* S   = (u16*)(ws);
  u16* qb  = (u16*)(ws + 64 * MB);
  u16* kb  = (u16*)(ws + 72 * MB);
  u16* vT  = (u16*)(ws + 80 * MB);
  u16* P   = (u16*)(ws + 88 * MB);

  hipMemsetAsync((char*)out + (size_t)2048 * DIM * 4, 0, (size_t)2048 * DIM * 4, stream);

  cvt6<<<dim3(NTOK * DIM / (256 * 8), 1, 6), 256, 0, stream>>>(
      qx, kx, vx, Wq, Wk, Wv, qxb, kxb, vxb, Wqb, Wkb, Wvb);

  proj_sw<<<768, 256, 0, stream>>>(qxb, kxb, vxb, Wqb, Wkb, Wvb, qb, kb, vT);

  gemm_scores<<<528, 256, 0, stream>>>(qb, kb, S, 0.03125f);

  softmax_causal<<<NTOK, 256, 0, stream>>>(S, P);

  gemm_pv<<<768, 256, 0, stream>>>(P, vT, out);
}

// Round 8
// 138.279 us; speedup vs baseline: 1.0235x; 1.0235x over previous
//
#include <hip/hip_runtime.h>
#include <hip/hip_bf16.h>
#include <stdint.h>

#define NTOK 4096
#define DIM  1024

typedef unsigned short u16;
typedef __bf16 bf16x8 __attribute__((ext_vector_type(8)));
typedef float f32x4 __attribute__((ext_vector_type(4)));
typedef u16 u16x8 __attribute__((ext_vector_type(8)));

// ---------- helpers ----------
__device__ __forceinline__ u16 f2bf(float f) {
  union { float f; uint32_t u; } c; c.f = f;
  return (u16)((c.u + 0x7fffu + ((c.u >> 16) & 1u)) >> 16);  // RNE
}
__device__ __forceinline__ float bf2f(u16 b) {
  union { uint32_t u; float f; } c; c.u = (uint32_t)b << 16;
  return c.f;
}

__device__ __forceinline__ float wave_max(float v) {
#pragma unroll
  for (int o = 32; o; o >>= 1) v = fmaxf(v, __shfl_xor(v, o, 64));
  return v;
}
__device__ __forceinline__ float wave_sum(float v) {
#pragma unroll
  for (int o = 32; o; o >>= 1) v += __shfl_xor(v, o, 64);
  return v;
}

// bijective XCD swizzle (m204)
__device__ __forceinline__ int xcd_swz(int orig, int nwg) {
  const int q = nwg >> 3, r = nwg & 7;
  const int x = orig & 7, i = orig >> 3;
  return (x < r ? x * (q + 1) : r * (q + 1) + (x - r) * q) + i;
}

// async global->LDS, 16B/lane; LDS dest wave-uniform base (HW adds lane*16).
__device__ __forceinline__ void gld16(const u16* g, u16* l) {
  __builtin_amdgcn_global_load_lds((const __attribute__((address_space(1))) void*)g,
                                   (__attribute__((address_space(3))) void*)l, 16, 0, 0);
}

template<int N> __device__ __forceinline__ void wait_vmcnt() {
  if constexpr (N == 0) asm volatile("s_waitcnt vmcnt(0)" ::: "memory");
  else if constexpr (N == 6) asm volatile("s_waitcnt vmcnt(6)" ::: "memory");
  else if constexpr (N == 8) asm volatile("s_waitcnt vmcnt(8)" ::: "memory");
}

// ============================================================================
// fp32 -> bf16 conversion, 8 elems/thread. z selects tensor.
// ============================================================================
__global__ __launch_bounds__(256) void cvt6(
    const float* __restrict__ qx, const float* __restrict__ kx, const float* __restrict__ vx,
    const float* __restrict__ Wq, const float* __restrict__ Wk, const float* __restrict__ Wv,
    u16* __restrict__ qxb, u16* __restrict__ kxb, u16* __restrict__ vxb,
    u16* __restrict__ Wqb, u16* __restrict__ Wkb, u16* __restrict__ Wvb)
{
  const int z = blockIdx.z;
  const int nelem = (z < 3) ? NTOK * DIM : DIM * DIM;
  const int i = (blockIdx.x * 256 + threadIdx.x) * 8;
  if (i >= nelem) return;
  const float* in = (z == 0) ? qx : (z == 1) ? kx : (z == 2) ? vx
                  : (z == 3) ? Wq : (z == 4) ? Wk : Wv;
  u16* out = (z == 0) ? qxb : (z == 1) ? kxb : (z == 2) ? vxb
           : (z == 3) ? Wqb : (z == 4) ? Wkb : Wvb;
  float4 a = *reinterpret_cast<const float4*>(in + i);
  float4 b = *reinterpret_cast<const float4*>(in + i + 4);
  u16x8 o;
  o[0] = f2bf(a.x); o[1] = f2bf(a.y); o[2] = f2bf(a.z); o[3] = f2bf(a.w);
  o[4] = f2bf(b.x); o[5] = f2bf(b.y); o[6] = f2bf(b.z); o[7] = f2bf(b.w);
  *reinterpret_cast<u16x8*>(out + i) = o;
}

// ============================================================================
// BMx128xK core, 1-DEEP COUNTED-VMCNT double buffer (T4, minimal form).
// EXACTLY R5's proven-correct dataflow (stage(t+1) into buf^1 before compute
// of buf), but the barrier pair is now raw s_barrier + COUNTED vmcnt:
//   loop t: stage(t+1 -> buf^1)           (+LPS loads, 2*LPS in flight)
//           vmcnt(LPS)                    (tile t landed; t+1 stays in flight)
//           s_barrier; sched_barrier(0)
//           ds_read(buf) x{BM/32+4}; MFMA x{BM/8}   (t+1 loads fly under this)
//           s_barrier; sched_barrier(0)   (no vmcnt drain!)
// LPS = BM/32 + 4 loads/wave/tile (A: BM/32, B: 4). Last tile: vmcnt(0).
// BK=64; chunk-XOR swizzle (R3/R4-verified 0-conflict): LDS chunk c of row r
// holds global chunk c^(r&7); staging pre-swizzles the global source.
// ============================================================================
template<int BM>
__device__ __forceinline__ void mm_core(
    const u16* __restrict__ A, const u16* __restrict__ B,
    int lda, int ldb, int klo, int khi, int row0, int col0,
    u16* sA, u16* sB, f32x4 (&acc)[BM / 32][4])
{
  constexpr int RPWA = BM / 4;        // A rows staged per wave
  constexpr int ASZ = BM * 64;        // elems per A buffer
  constexpr int BSZ = 128 * 64;       // elems per B buffer
  constexpr int LPS = BM / 32 + 4;    // loads per wave per tile
  const int tid = threadIdx.x;
  const int wave = tid >> 6, lane = tid & 63;
  const int wr = wave >> 1, wc = wave & 1;
  const int l15 = lane & 15, l4 = lane >> 4;
  const int h = l15 & 7;

  const int srow = lane >> 3;
  const int scol = ((lane & 7) ^ (lane >> 3)) << 3;  // pre-swizzled global chunk
  const u16* gA = A + (size_t)(row0 + wave * RPWA + srow) * lda + scol;
  const u16* gB = B + (size_t)(col0 + wave * 32 + srow) * ldb + scol;
  const int lbA = wave * RPWA * 64;
  const int lbB = wave * 32 * 64;

  auto stage = [&](int k0, u16* bA, u16* bB) {
#pragma unroll
    for (int i = 0; i < BM / 32; ++i)
      gld16(gA + (size_t)(i * 8) * lda + k0, bA + lbA + i * 512);
#pragma unroll
    for (int i = 0; i < 4; ++i)
      gld16(gB + (size_t)(i * 8) * ldb + k0, bB + lbB + i * 512);
  };

  stage(klo, sA, sB);  // prologue -> buffer 0
  int cur = 0;
  for (int k0 = klo; k0 < khi; k0 += 64) {
    const bool more = (k0 + 64 < khi);
    if (more) {
      stage(k0 + 64, sA + (cur ^ 1) * ASZ, sB + (cur ^ 1) * BSZ);
      wait_vmcnt<LPS>();   // tile t complete; tile t+1's LPS loads in flight
    } else {
      wait_vmcnt<0>();
    }
    __builtin_amdgcn_s_barrier();
    __builtin_amdgcn_sched_barrier(0);

    const char* bA = (const char*)(sA + cur * ASZ);
    const char* bB = (const char*)(sB + cur * BSZ);
#pragma unroll
    for (int ks = 0; ks < 2; ++ks) {
      bf16x8 af[BM / 32], bfv[4];
#pragma unroll
      for (int mf = 0; mf < BM / 32; ++mf)
        af[mf] = *reinterpret_cast<const bf16x8*>(
            bA + ((wr * (BM / 2) + mf * 16 + l15) << 7) + ((((ks << 2) + l4) ^ h) << 4));
#pragma unroll
      for (int nf = 0; nf < 4; ++nf)
        bfv[nf] = *reinterpret_cast<const bf16x8*>(
            bB + ((wc * 64 + nf * 16 + l15) << 7) + ((((ks << 2) + l4) ^ h) << 4));
#pragma unroll
      for (int mf = 0; mf < BM / 32; ++mf)
#pragma unroll
        for (int nf = 0; nf < 4; ++nf)
          acc[mf][nf] = __builtin_amdgcn_mfma_f32_16x16x32_bf16(af[mf], bfv[nf], acc[mf][nf], 0, 0, 0);
    }

    __builtin_amdgcn_s_barrier();      // raw: tile t+1 loads stay in flight
    __builtin_amdgcn_sched_barrier(0);
    cur ^= 1;
  }
}

// ============================================================================
// Projections: y = x @ W^T, bf16 in/out. 1-D grid 768 = 3 x (32by x 8bx),
// XCD-swizzled. z=2 stores v transposed [DIM,NTOK] for the PV B-operand.
// ============================================================================
__global__ __launch_bounds__(256) void proj_sw(
    const u16* __restrict__ qxb, const u16* __restrict__ kxb, const u16* __restrict__ vxb,
    const u16* __restrict__ Wqb, const u16* __restrict__ Wkb, const u16* __restrict__ Wvb,
    u16* __restrict__ qb, u16* __restrict__ kb, u16* __restrict__ vT)
{
  __shared__ alignas(16) u16 sA[2 * 128 * 64];
  __shared__ alignas(16) u16 sB[2 * 128 * 64];
  const int w = xcd_swz(blockIdx.x, 768);
  const int z = w >> 8, rem = w & 255;
  const int by = rem >> 3, bx = rem & 7;
  const u16* A = (z == 0) ? qxb : (z == 1) ? kxb : vxb;
  const u16* B = (z == 0) ? Wqb : (z == 1) ? Wkb : Wvb;
  const int row0 = by * 128, col0 = bx * 128;

  f32x4 acc[4][4] = {};
  mm_core<128>(A, B, DIM, DIM, 0, DIM, row0, col0, sA, sB, acc);

  const int lane = threadIdx.x & 63;
  const int wave = threadIdx.x >> 6;
  const int l15 = lane & 15, l4 = lane >> 4;
  const int om = row0 + (wave >> 1) * 64;
  const int on = col0 + (wave & 1) * 64;
  if (z < 2) {
    u16* C = (z == 0) ? qb : kb;
#pragma unroll
    for (int mf = 0; mf < 4; ++mf)
#pragma unroll
      for (int nf = 0; nf < 4; ++nf)
#pragma unroll
        for (int r = 0; r < 4; ++r)
          C[(size_t)(om + mf * 16 + l4 * 4 + r) * DIM + (on + nf * 16 + l15)] = f2bf(acc[mf][nf][r]);
  } else {  // v transposed: 4 consecutive rows -> contiguous 8B store
#pragma unroll
    for (int mf = 0; mf < 4; ++mf)
#pragma unroll
      for (int nf = 0; nf < 4; ++nf) {
        ushort4 o;
        o.x = f2bf(acc[mf][nf][0]);
        o.y = f2bf(acc[mf][nf][1]);
        o.z = f2bf(acc[mf][nf][2]);
        o.w = f2bf(acc[mf][nf][3]);
        *reinterpret_cast<ushort4*>(&vT[(size_t)(on + nf * 16 + l15) * NTOK + (om + mf * 16 + l4 * 4)]) = o;
      }
  }
}

// ============================================================================
// Scores: S = (q @ k^T) * scale, bf16 out. 528 lower-triangle tiles.
// ============================================================================
__global__ __launch_bounds__(256) void gemm_scores(
    const u16* __restrict__ A, const u16* __restrict__ B, u16* __restrict__ C, float scale)
{
  __shared__ alignas(16) u16 sA[2 * 128 * 64];
  __shared__ alignas(16) u16 sB[2 * 128 * 64];
  const int t = xcd_swz(blockIdx.x, 528);
  int by = (int)((sqrtf(8.0f * t + 1.0f) - 1.0f) * 0.5f);
  while ((by + 1) * (by + 2) / 2 <= t) ++by;
  while (by * (by + 1) / 2 > t) --by;
  const int bx = t - by * (by + 1) / 2;
  const int row0 = by * 128, col0 = bx * 128;

  f32x4 acc[4][4] = {};
  mm_core<128>(A, B, DIM, DIM, 0, DIM, row0, col0, sA, sB, acc);

  const int lane = threadIdx.x & 63;
  const int wave = threadIdx.x >> 6;
  const int l15 = lane & 15, l4 = lane >> 4;
  const int om = row0 + (wave >> 1) * 64;
  const int on = col0 + (wave & 1) * 64;
#pragma unroll
  for (int mf = 0; mf < 4; ++mf)
#pragma unroll
    for (int nf = 0; nf < 4; ++nf)
#pragma unroll
      for (int r = 0; r < 4; ++r)
        C[(size_t)(om + mf * 16 + l4 * 4 + r) * NTOK + (on + nf * 16 + l15)] = f2bf(acc[mf][nf][r] * scale);
}

// ============================================================================
// PV: out = P @ vT^T. 64x128 tiles, 1-D grid 768 = 96 chunks x 8 bx.
// by<32: single chunk. by>=32: 2-way split-K, both halves atomicAdd into
// pre-zeroed out (2 addends -> commutative -> deterministic).
// ============================================================================
__global__ __launch_bounds__(256) void gemm_pv(
    const u16* __restrict__ P, const u16* __restrict__ vT, float* __restrict__ C)
{
  __shared__ alignas(16) u16 sA[2 * 64 * 64];
  __shared__ alignas(16) u16 sB[2 * 128 * 64];
  const int w = xcd_swz(blockIdx.x, 768);
  const int bx = w & 7;
  const int cid = w >> 3;  // 0..95
  int by, half;
  if (cid < 32) { by = cid; half = -1; }
  else { const int j = cid - 32; by = 32 + (j >> 1); half = j & 1; }
  const int row0 = by * 64, col0 = bx * 128;
  const int Klim = row0 + 64;
  int klo = 0, khi = Klim;
  if (half >= 0) {
    const int h1 = (((Klim >> 6) + 1) >> 1) << 6;
    if (half == 0) khi = h1; else klo = h1;
  }

  f32x4 acc[2][4] = {};
  mm_core<64>(P, vT, NTOK, NTOK, klo, khi, row0, col0, sA, sB, acc);

  const int lane = threadIdx.x & 63;
  const int wave = threadIdx.x >> 6;
  const int l15 = lane & 15, l4 = lane >> 4;
  const int om = row0 + (wave >> 1) * 32;
  const int on = col0 + (wave & 1) * 64;
#pragma unroll
  for (int mf = 0; mf < 2; ++mf)
#pragma unroll
    for (int nf = 0; nf < 4; ++nf)
#pragma unroll
      for (int r = 0; r < 4; ++r) {
        const size_t idx = (size_t)(om + mf * 16 + l4 * 4 + r) * DIM + (on + nf * 16 + l15);
        if (half >= 0) atomicAdd(&C[idx], acc[mf][nf][r]);
        else C[idx] = acc[mf][nf][r];
      }
}

// ---------- causal row softmax: S bf16 -> P bf16, cols < (row&~127)+128 ----------
__global__ __launch_bounds__(256) void softmax_causal(const u16* __restrict__ S,
                                                      u16* __restrict__ P) {
  __shared__ float buf[NTOK];
  __shared__ float red[8];
  const int row = blockIdx.x;
  const int tid = threadIdx.x;
  const int limit = row + 1;
  const int limit128 = (row & ~127) + 128;
  const u16* srow = S + (size_t)row * NTOK;

  float lmax = -1e30f;
  for (int j = tid * 8; j < limit128; j += 2048) {
    float v[8];
    if (j + 8 <= limit) {
      u16x8 sv = *reinterpret_cast<const u16x8*>(srow + j);
#pragma unroll
      for (int e = 0; e < 8; ++e) v[e] = bf2f(sv[e]);
    } else {
#pragma unroll
      for (int e = 0; e < 8; ++e) v[e] = (j + e < limit) ? bf2f(srow[j + e]) : -1e30f;
    }
    float4 lo = {v[0], v[1], v[2], v[3]}, hi = {v[4], v[5], v[6], v[7]};
    *reinterpret_cast<float4*>(buf + j) = lo;
    *reinterpret_cast<float4*>(buf + j + 4) = hi;
#pragma unroll
    for (int e = 0; e < 8; ++e) lmax = fmaxf(lmax, v[e]);
  }
  lmax = wave_max(lmax);
  if ((tid & 63) == 0) red[tid >> 6] = lmax;
  __syncthreads();
  const float m = fmaxf(fmaxf(red[0], red[1]), fmaxf(red[2], red[3]));

  float lsum = 0.f;
  for (int j = tid * 8; j < limit128; j += 2048) {
    float4 lo = *reinterpret_cast<float4*>(buf + j);
    float4 hi = *reinterpret_cast<float4*>(buf + j + 4);
    float e0 = __expf(lo.x - m), e1 = __expf(lo.y - m), e2 = __expf(lo.z - m), e3 = __expf(lo.w - m);
    float e4 = __expf(hi.x - m), e5 = __expf(hi.y - m), e6 = __expf(hi.z - m), e7 = __expf(hi.w - m);
    float4 eo = {e0, e1, e2, e3}, eh = {e4, e5, e6, e7};
    *reinterpret_cast<float4*>(buf + j) = eo;
    *reinterpret_cast<float4*>(buf + j + 4) = eh;
    lsum += ((e0 + e1) + (e2 + e3)) + ((e4 + e5) + (e6 + e7));
  }
  lsum = wave_sum(lsum);
  if ((tid & 63) == 0) red[4 + (tid >> 6)] = lsum;
  __syncthreads();
  const float inv = 1.0f / (red[4] + red[5] + red[6] + red[7]);

  u16* prow = P + (size_t)row * NTOK;
  for (int j = tid * 8; j < limit128; j += 2048) {
    float4 lo = *reinterpret_cast<float4*>(buf + j);
    float4 hi = *reinterpret_cast<float4*>(buf + j + 4);
    u16x8 o;
    o[0] = f2bf(lo.x * inv); o[1] = f2bf(lo.y * inv);
    o[2] = f2bf(lo.z * inv); o[3] = f2bf(lo.w * inv);
    o[4] = f2bf(hi.x * inv); o[5] = f2bf(hi.y * inv);
    o[6] = f2bf(hi.z * inv); o[7] = f2bf(hi.w * inv);
    *reinterpret_cast<u16x8*>(prow + j) = o;
  }
}

// ---------- launcher ----------
extern "C" void kernel_launch(void* const* d_in, const int* in_sizes, int n_in,
                              void* d_out, int out_size, void* d_ws, size_t ws_size,
                              hipStream_t stream) {
  const float* qx = (const float*)d_in[0];
  const float* kx = (const float*)d_in[1];
  const float* vx = (const float*)d_in[2];
  const float* Wq = (const float*)d_in[3];
  const float* Wk = (const float*)d_in[4];
  const float* Wv = (const float*)d_in[5];
  float* out = (float*)d_out;
  char* ws = (char*)d_ws;
  const size_t MB = 1024ull * 1024ull;

  if (ws_size < 120 * MB) {
    hipMemsetAsync(d_out, 0xFF, (size_t)out_size * sizeof(float), stream);
    return;
  }

  // ws layout: [0,30) cvt bf16 (dead after proj) | [0,32) S bf16 (after proj)
  //            [64,72) qb | [72,80) kb | [80,88) vT | [88,120) P
  u16* qxb = (u16*)(ws);
  u16* kxb = (u16*)(ws + 8 * MB);
  u16* vxb = (u16*)(ws + 16 * MB);
  u16* Wqb = (u16*)(ws + 24 * MB);
  u16* Wkb = (u16*)(ws + 26 * MB);
  u16* Wvb = (u16*)(ws + 28 * MB);
  u16* S   = (u16*)(ws);
  u16* qb  = (u16*)(ws + 64 * MB);
  u16* kb  = (u16*)(ws + 72 * MB);
  u16* vT  = (u16*)(ws + 80 * MB);
  u16* P   = (u16*)(ws + 88 * MB);

  hipMemsetAsync((char*)out + (size_t)2048 * DIM * 4, 0, (size_t)2048 * DIM * 4, stream);

  cvt6<<<dim3(NTOK * DIM / (256 * 8), 1, 6), 256, 0, stream>>>(
      qx, kx, vx, Wq, Wk, Wv, qxb, kxb, vxb, Wqb, Wkb, Wvb);

  proj_sw<<<768, 256, 0, stream>>>(qxb, kxb, vxb, Wqb, Wkb, Wvb, qb, kb, vT);

  gemm_scores<<<528, 256, 0, stream>>>(qb, kb, S, 0.03125f);

  softmax_causal<<<NTOK, 256, 0, stream>>>(S, P);

  gemm_pv<<<768, 256, 0, stream>>>(P, vT, out);
}